// Round 1
// baseline (363.335 us; speedup 1.0000x reference)
//
#include <hip/hip_runtime.h>
#include <math.h>

#define BS 8
#define NN 1024
#define FIN 256
#define HEADS 8
#define FO 64
#define NH (HEADS*FO)   /* 512 */
static constexpr float ALPHA = 0.2f;

// ---------------------------------------------------------------------------
// Kernel 1: Wh = h @ W   (M=8192, K=256, N=512), f32 tiled GEMM
// 64x64 tile, 256 threads, 4x4 micro-tile, K-step 16
// ---------------------------------------------------------------------------
__global__ __launch_bounds__(256) void gemm_wh(const float* __restrict__ h,
                                               const float* __restrict__ W,
                                               float* __restrict__ Wh) {
    __shared__ float As[16][65];   // [k][m], padded to kill write conflicts
    __shared__ float Bs[16][64];   // [k][n]
    const int t  = threadIdx.x;
    const int n0 = blockIdx.x * 64;
    const int m0 = blockIdx.y * 64;
    const int tm = t >> 4, tn = t & 15;
    float acc[4][4] = {};

    for (int k0 = 0; k0 < FIN; k0 += 16) {
        // A tile: thread t loads 4 consecutive k for row mm
        {
            const int mm  = t >> 2;
            const int kk4 = (t & 3) * 4;
            const float4 v = *reinterpret_cast<const float4*>(
                &h[(size_t)(m0 + mm) * FIN + k0 + kk4]);
            As[kk4 + 0][mm] = v.x; As[kk4 + 1][mm] = v.y;
            As[kk4 + 2][mm] = v.z; As[kk4 + 3][mm] = v.w;
        }
        // B tile: 4 rows of 64, coalesced
        {
            const int nn = t & 63;
            const int kb = t >> 6;
            #pragma unroll
            for (int q = 0; q < 4; ++q) {
                const int kk = kb + q * 4;
                Bs[kk][nn] = W[(size_t)(k0 + kk) * NH + n0 + nn];
            }
        }
        __syncthreads();
        #pragma unroll
        for (int kk = 0; kk < 16; ++kk) {
            const float a0 = As[kk][tm * 4 + 0];
            const float a1 = As[kk][tm * 4 + 1];
            const float a2 = As[kk][tm * 4 + 2];
            const float a3 = As[kk][tm * 4 + 3];
            const float4 b = *reinterpret_cast<const float4*>(&Bs[kk][tn * 4]);
            acc[0][0] += a0 * b.x; acc[0][1] += a0 * b.y; acc[0][2] += a0 * b.z; acc[0][3] += a0 * b.w;
            acc[1][0] += a1 * b.x; acc[1][1] += a1 * b.y; acc[1][2] += a1 * b.z; acc[1][3] += a1 * b.w;
            acc[2][0] += a2 * b.x; acc[2][1] += a2 * b.y; acc[2][2] += a2 * b.z; acc[2][3] += a2 * b.w;
            acc[3][0] += a3 * b.x; acc[3][1] += a3 * b.y; acc[3][2] += a3 * b.z; acc[3][3] += a3 * b.w;
        }
        __syncthreads();
    }
    #pragma unroll
    for (int i2 = 0; i2 < 4; ++i2) {
        float4 v = make_float4(acc[i2][0], acc[i2][1], acc[i2][2], acc[i2][3]);
        *reinterpret_cast<float4*>(
            &Wh[(size_t)(m0 + tm * 4 + i2) * NH + n0 + tn * 4]) = v;
    }
}

// ---------------------------------------------------------------------------
// Kernel 2: e_src[b,i,h] = dot(Wh[b,i,h,:], a_src[h,:])
//           e_dst[b,h,i] = dot(Wh[b,i,h,:], a_dst[h,:])
// one block per (b,i), 512 threads; wave w == head w
// ---------------------------------------------------------------------------
__global__ __launch_bounds__(512) void calc_e(const float* __restrict__ Wh,
                                              const float* __restrict__ a,
                                              float* __restrict__ esrc,
                                              float* __restrict__ edst) {
    const int t  = threadIdx.x;
    const int bi = blockIdx.x;          // b*NN + i
    const int hh = t >> 6, f = t & 63;
    const float wh = Wh[(size_t)bi * NH + t];
    float ps = wh * a[hh * 128 + f];
    float pd = wh * a[hh * 128 + 64 + f];
    #pragma unroll
    for (int off = 32; off > 0; off >>= 1) {
        ps += __shfl_down(ps, off);
        pd += __shfl_down(pd, off);
    }
    if (f == 0) {
        const int b = bi >> 10, i = bi & (NN - 1);
        esrc[bi * HEADS + hh]            = ps;   // [b][i][h]
        edst[(b * HEADS + hh) * NN + i]  = pd;   // [b][h][j]
    }
}

// ---------------------------------------------------------------------------
// Kernel 3: per-row softmax stats (max m, 1/sum) — one wave per (b,i),
// all 8 heads together so adj row is read once.
// ---------------------------------------------------------------------------
__global__ __launch_bounds__(256) void softmax_stats(const int* __restrict__ adj,
                                                     const float* __restrict__ esrc,
                                                     const float* __restrict__ edst,
                                                     float* __restrict__ mrow,
                                                     float* __restrict__ linv) {
    const int wave = (blockIdx.x * 256 + threadIdx.x) >> 6;   // b*NN + i
    const int lane = threadIdx.x & 63;
    const int b = wave >> 10;
    float es[HEADS];
    #pragma unroll
    for (int hh = 0; hh < HEADS; ++hh) es[hh] = esrc[wave * HEADS + hh];

    float m8[HEADS], l8[HEADS];
    #pragma unroll
    for (int hh = 0; hh < HEADS; ++hh) { m8[hh] = -INFINITY; l8[hh] = 0.f; }

    const int* adjrow = adj + (size_t)wave * NN;
    for (int jt = 0; jt < NN; jt += 64) {
        const int j  = jt + lane;
        const int av = adjrow[j];
        if (av != 0) {
            #pragma unroll
            for (int hh = 0; hh < HEADS; ++hh) {
                float e = es[hh] + edst[(b * HEADS + hh) * NN + j];
                e = e > 0.f ? e : ALPHA * e;
                const float nm = fmaxf(m8[hh], e);
                l8[hh] = l8[hh] * __expf(m8[hh] - nm) + __expf(e - nm);
                m8[hh] = nm;
            }
        }
    }
    #pragma unroll
    for (int hh = 0; hh < HEADS; ++hh) {
        float m = m8[hh], l = l8[hh];
        #pragma unroll
        for (int off = 32; off > 0; off >>= 1) {
            const float mo = __shfl_xor(m, off);
            const float lo = __shfl_xor(l, off);
            const float nm = fmaxf(m, mo);
            const float w1 = (m  == nm) ? 1.f : __expf(m  - nm);
            const float w2 = (mo == nm) ? 1.f : __expf(mo - nm);
            l = l * w1 + lo * w2;
            m = nm;
        }
        if (lane == 0) {
            mrow[wave * HEADS + hh] = m;         // [b][i][h]
            linv[wave * HEADS + hh] = 1.f / l;
        }
    }
}

// ---------------------------------------------------------------------------
// Kernel 4: h_prime[b,i,h,f] = (1/l) * sum_j exp(e_ij - m) * Wh[b,j,h,f]
// block = (b, 8-row i-tile), 512 threads = (h,f). p staged in LDS.
// ---------------------------------------------------------------------------
#define IT 8
__global__ __launch_bounds__(512) void attn_pv(const int* __restrict__ adj,
                                               const float* __restrict__ Wh,
                                               const float* __restrict__ esrc,
                                               const float* __restrict__ edst,
                                               const float* __restrict__ mrow,
                                               const float* __restrict__ linv,
                                               float* __restrict__ out) {
    __shared__ float p_lds[IT * HEADS * 32];     // [ii][h][jl]
    __shared__ float s_es[IT][HEADS], s_m[IT][HEADS], s_li[IT][HEADS];
    const int t  = threadIdx.x;
    const int bb = blockIdx.x;                   // 0..1023
    const int b  = bb >> 7;
    const int i0 = (bb & 127) * IT;
    const int hh = t >> 6;

    if (t < IT * HEADS) {
        const int ii = t >> 3, h2 = t & 7;
        const int row = (b * NN + i0 + ii) * HEADS + h2;
        s_es[ii][h2] = esrc[row];
        s_m [ii][h2] = mrow[row];
        s_li[ii][h2] = linv[row];
    }
    __syncthreads();

    float acc[IT] = {};
    for (int jt = 0; jt < NN; jt += 32) {
        // compute p for this j-tile: 8i x 8h x 32j = 2048 entries, 4/thread
        #pragma unroll
        for (int k = 0; k < 4; ++k) {
            const int idx = k * 512 + t;
            const int ii  = idx >> 8;
            const int h2  = (idx >> 5) & 7;
            const int jl  = idx & 31;
            const int j   = jt + jl;
            const int av  = adj[(size_t)(b * NN + i0 + ii) * NN + j];
            float e = s_es[ii][h2] + edst[(b * HEADS + h2) * NN + j];
            e = e > 0.f ? e : ALPHA * e;
            p_lds[idx] = av ? __expf(e - s_m[ii][h2]) : 0.f;
        }
        __syncthreads();

        const float* whp = &Wh[(size_t)(b * NN + jt) * NH + t];
        #pragma unroll 8
        for (int jl = 0; jl < 32; ++jl) {
            const float wh = whp[(size_t)jl * NH];
            const float* pp = &p_lds[hh * 32 + jl];
            #pragma unroll
            for (int ii = 0; ii < IT; ++ii)
                acc[ii] += pp[ii * HEADS * 32] * wh;
        }
        __syncthreads();
    }
    #pragma unroll
    for (int ii = 0; ii < IT; ++ii)
        out[(size_t)(b * NN + i0 + ii) * NH + t] = acc[ii] * s_li[ii][hh];
}

// ---------------------------------------------------------------------------
extern "C" void kernel_launch(void* const* d_in, const int* in_sizes, int n_in,
                              void* d_out, int out_size, void* d_ws, size_t ws_size,
                              hipStream_t stream) {
    const float* h   = (const float*)d_in[0];
    const int*   adj = (const int*)  d_in[1];
    const float* W   = (const float*)d_in[2];
    const float* a   = (const float*)d_in[3];
    float* out = (float*)d_out;

    float* ws   = (float*)d_ws;
    float* Wh   = ws;                                  // 8192*512
    float* esrc = Wh   + (size_t)BS * NN * NH;         // 8192*8
    float* edst = esrc + (size_t)BS * NN * HEADS;      // 8192*8
    float* mrow = edst + (size_t)BS * NN * HEADS;      // 8192*8
    float* lin  = mrow + (size_t)BS * NN * HEADS;      // 8192*8

    gemm_wh      <<<dim3(NH / 64, (BS * NN) / 64), 256, 0, stream>>>(h, W, Wh);
    calc_e       <<<BS * NN, 512, 0, stream>>>(Wh, a, esrc, edst);
    softmax_stats<<<(BS * NN) / 4, 256, 0, stream>>>(adj, esrc, edst, mrow, lin);
    attn_pv      <<<(BS * NN) / IT, 512, 0, stream>>>(adj, Wh, esrc, edst, mrow, lin, out);
}

// Round 2
// 168.335 us; speedup vs baseline: 2.1584x; 2.1584x over previous
//
#include <hip/hip_runtime.h>
#include <hip/hip_bf16.h>
#include <math.h>

#define BS 8
#define NN 1024
#define FIN 256
#define HEADS 8
#define FO 64
#define NH (HEADS*FO)   /* 512 */
static constexpr float ALPHA = 0.2f;

typedef short bf16x8 __attribute__((ext_vector_type(8)));
typedef float f32x4  __attribute__((ext_vector_type(4)));

// ---------------------------------------------------------------------------
// Kernel 1: Wh = h @ W   (M=8192, K=256, N=512), f32 tiled GEMM
// ---------------------------------------------------------------------------
__global__ __launch_bounds__(256) void gemm_wh(const float* __restrict__ h,
                                               const float* __restrict__ W,
                                               float* __restrict__ Wh) {
    __shared__ float As[16][65];
    __shared__ float Bs[16][64];
    const int t  = threadIdx.x;
    const int n0 = blockIdx.x * 64;
    const int m0 = blockIdx.y * 64;
    const int tm = t >> 4, tn = t & 15;
    float acc[4][4] = {};

    for (int k0 = 0; k0 < FIN; k0 += 16) {
        {
            const int mm  = t >> 2;
            const int kk4 = (t & 3) * 4;
            const float4 v = *reinterpret_cast<const float4*>(
                &h[(size_t)(m0 + mm) * FIN + k0 + kk4]);
            As[kk4 + 0][mm] = v.x; As[kk4 + 1][mm] = v.y;
            As[kk4 + 2][mm] = v.z; As[kk4 + 3][mm] = v.w;
        }
        {
            const int nn = t & 63;
            const int kb = t >> 6;
            #pragma unroll
            for (int q = 0; q < 4; ++q) {
                const int kk = kb + q * 4;
                Bs[kk][nn] = W[(size_t)(k0 + kk) * NH + n0 + nn];
            }
        }
        __syncthreads();
        #pragma unroll
        for (int kk = 0; kk < 16; ++kk) {
            const float a0 = As[kk][tm * 4 + 0];
            const float a1 = As[kk][tm * 4 + 1];
            const float a2 = As[kk][tm * 4 + 2];
            const float a3 = As[kk][tm * 4 + 3];
            const float4 b = *reinterpret_cast<const float4*>(&Bs[kk][tn * 4]);
            acc[0][0] += a0 * b.x; acc[0][1] += a0 * b.y; acc[0][2] += a0 * b.z; acc[0][3] += a0 * b.w;
            acc[1][0] += a1 * b.x; acc[1][1] += a1 * b.y; acc[1][2] += a1 * b.z; acc[1][3] += a1 * b.w;
            acc[2][0] += a2 * b.x; acc[2][1] += a2 * b.y; acc[2][2] += a2 * b.z; acc[2][3] += a2 * b.w;
            acc[3][0] += a3 * b.x; acc[3][1] += a3 * b.y; acc[3][2] += a3 * b.z; acc[3][3] += a3 * b.w;
        }
        __syncthreads();
    }
    #pragma unroll
    for (int i2 = 0; i2 < 4; ++i2) {
        float4 v = make_float4(acc[i2][0], acc[i2][1], acc[i2][2], acc[i2][3]);
        *reinterpret_cast<float4*>(
            &Wh[(size_t)(m0 + tm * 4 + i2) * NH + n0 + tn * 4]) = v;
    }
}

// ---------------------------------------------------------------------------
// Kernel 2: e_src / e_dst
// ---------------------------------------------------------------------------
__global__ __launch_bounds__(512) void calc_e(const float* __restrict__ Wh,
                                              const float* __restrict__ a,
                                              float* __restrict__ esrc,
                                              float* __restrict__ edst) {
    const int t  = threadIdx.x;
    const int bi = blockIdx.x;
    const int hh = t >> 6, f = t & 63;
    const float wh = Wh[(size_t)bi * NH + t];
    float ps = wh * a[hh * 128 + f];
    float pd = wh * a[hh * 128 + 64 + f];
    #pragma unroll
    for (int off = 32; off > 0; off >>= 1) {
        ps += __shfl_down(ps, off);
        pd += __shfl_down(pd, off);
    }
    if (f == 0) {
        const int b = bi >> 10, i = bi & (NN - 1);
        esrc[bi * HEADS + hh]            = ps;
        edst[(b * HEADS + hh) * NN + i]  = pd;
    }
}

// ---------------------------------------------------------------------------
// Kernel 2b: pack adjacency into bitmask via ballot (32 MB -> 1 MB)
// ---------------------------------------------------------------------------
__global__ __launch_bounds__(256) void pack_adj(const int* __restrict__ adj,
                                                unsigned* __restrict__ bits) {
    const size_t gid = (size_t)blockIdx.x * 256 + threadIdx.x;
    const int av = adj[gid];
    const unsigned long long mask = __ballot(av != 0);
    const int lane = threadIdx.x & 63;
    if ((lane & 31) == 0)
        bits[gid >> 5] = (unsigned)(lane ? (mask >> 32) : mask);
}

// ---------------------------------------------------------------------------
// Kernel 3: per-row softmax stats (m, 1/l) — one wave per (b,i), bitmask adj
// ---------------------------------------------------------------------------
__global__ __launch_bounds__(256) void softmax_stats(const unsigned* __restrict__ bits,
                                                     const float* __restrict__ esrc,
                                                     const float* __restrict__ edst,
                                                     float* __restrict__ mrow,
                                                     float* __restrict__ linv) {
    const int wave = (blockIdx.x * 256 + threadIdx.x) >> 6;   // b*NN + i
    const int lane = threadIdx.x & 63;
    const int b = wave >> 10;
    float es[HEADS];
    #pragma unroll
    for (int hh = 0; hh < HEADS; ++hh) es[hh] = esrc[wave * HEADS + hh];

    float m8[HEADS], l8[HEADS];
    #pragma unroll
    for (int hh = 0; hh < HEADS; ++hh) { m8[hh] = -INFINITY; l8[hh] = 0.f; }

    const unsigned* bitrow = bits + (size_t)wave * 32;
    for (int jt = 0; jt < NN; jt += 64) {
        const int j = jt + lane;
        const int on = (bitrow[j >> 5] >> (j & 31)) & 1;
        if (on) {
            #pragma unroll
            for (int hh = 0; hh < HEADS; ++hh) {
                float e = es[hh] + edst[(b * HEADS + hh) * NN + j];
                e = fmaxf(e, ALPHA * e);
                const float nm = fmaxf(m8[hh], e);
                l8[hh] = l8[hh] * __expf(m8[hh] - nm) + __expf(e - nm);
                m8[hh] = nm;
            }
        }
    }
    #pragma unroll
    for (int hh = 0; hh < HEADS; ++hh) {
        float m = m8[hh], l = l8[hh];
        #pragma unroll
        for (int off = 32; off > 0; off >>= 1) {
            const float mo = __shfl_xor(m, off);
            const float lo = __shfl_xor(l, off);
            const float nm = fmaxf(m, mo);
            const float w1 = (m  == nm) ? 1.f : __expf(m  - nm);
            const float w2 = (mo == nm) ? 1.f : __expf(mo - nm);
            l = l * w1 + lo * w2;
            m = nm;
        }
        if (lane == 0) {
            mrow[wave * HEADS + hh] = m;
            linv[wave * HEADS + hh] = 1.f / l;
        }
    }
}

// ---------------------------------------------------------------------------
// Kernel 4: PV via bf16 MFMA. Block = (b, h, 64-row i-tile), 4 waves.
// Wave w owns rows i0+w*16..+15 (x 64 f). P generated in-register in the
// A-fragment layout; Wh head-slice staged transposed+padded in LDS as bf16.
// ---------------------------------------------------------------------------
__global__ __launch_bounds__(256) void attn_pv_mfma(const unsigned* __restrict__ bits,
                                                    const float* __restrict__ Wh,
                                                    const float* __restrict__ esrc,
                                                    const float* __restrict__ edst,
                                                    const float* __restrict__ mrow,
                                                    const float* __restrict__ linv,
                                                    float* __restrict__ out) {
    __shared__ unsigned short Bs[64][72];   // [f][j], pad 8 -> 144B row stride
    const int t    = threadIdx.x;
    const int wv   = t >> 6;
    const int lane = t & 63;
    const int it   = blockIdx.x;            // 0..15
    const int h    = blockIdx.y;
    const int b    = blockIdx.z;
    const int i0   = it * 64;
    const int g    = lane >> 4;             // k-group 0..3
    const int l15  = lane & 15;

    const int row = i0 + wv * 16 + l15;     // A-fragment row for this lane
    const int gr  = b * NN + row;
    const float es_i = esrc[gr * HEADS + h];
    const float m_i  = mrow[gr * HEADS + h];
    const unsigned* bitrow = bits + (size_t)gr * 32;
    const float* ed = edst + (size_t)(b * HEADS + h) * NN;

    f32x4 acc[4] = {};

    // staging mapping: jp = j-pair (0..31), fc = f-chunk base (0,8,..,56)
    const int jp = t & 31;
    const int fc = (t >> 5) * 8;
    const float* whb = Wh + (size_t)(b * NN) * NH + h * 64 + fc;

    for (int j0 = 0; j0 < NN; j0 += 64) {
        __syncthreads();                    // protect Bs from previous reads
        {
            const float* r0 = whb + (size_t)(j0 + 2 * jp) * NH;
            const float* r1 = r0 + NH;
            const float4 a0 = *reinterpret_cast<const float4*>(r0);
            const float4 a1 = *reinterpret_cast<const float4*>(r0 + 4);
            const float4 c0 = *reinterpret_cast<const float4*>(r1);
            const float4 c1 = *reinterpret_cast<const float4*>(r1 + 4);
            #pragma unroll
            for (int q = 0; q < 8; ++q) {
                const float x = (q < 4) ? (&a0.x)[q] : (&a1.x)[q - 4];
                const float y = (q < 4) ? (&c0.x)[q] : (&c1.x)[q - 4];
                __hip_bfloat16 hx = __float2bfloat16(x);
                __hip_bfloat16 hy = __float2bfloat16(y);
                const unsigned pack = ((unsigned)*reinterpret_cast<unsigned short*>(&hy) << 16)
                                    |  (unsigned)*reinterpret_cast<unsigned short*>(&hx);
                *reinterpret_cast<unsigned*>(&Bs[fc + q][2 * jp]) = pack;
            }
        }
        __syncthreads();

        #pragma unroll
        for (int ks = 0; ks < 2; ++ks) {
            const int jb = j0 + ks * 32;
            // ---- A fragment: p values for k = 8g+q  (j = jb + 8g + q)
            const float4 d0 = *reinterpret_cast<const float4*>(ed + jb + 8 * g);
            const float4 d1 = *reinterpret_cast<const float4*>(ed + jb + 8 * g + 4);
            const unsigned word = bitrow[jb >> 5];
            const unsigned byte = (word >> (8 * g)) & 0xffu;
            bf16x8 af;
            #pragma unroll
            for (int q = 0; q < 8; ++q) {
                float e = es_i + ((q < 4) ? (&d0.x)[q] : (&d1.x)[q - 4]);
                e = fmaxf(e, ALPHA * e);
                const float p = ((byte >> q) & 1u) ? __expf(e - m_i) : 0.f;
                __hip_bfloat16 pb = __float2bfloat16(p);
                af[q] = *reinterpret_cast<short*>(&pb);
            }
            // ---- B fragments from LDS + MFMA
            #pragma unroll
            for (int n = 0; n < 4; ++n) {
                const int f = n * 16 + l15;
                const bf16x8 bf = *reinterpret_cast<const bf16x8*>(&Bs[f][ks * 32 + 8 * g]);
                acc[n] = __builtin_amdgcn_mfma_f32_16x16x32_bf16(af, bf, acc[n], 0, 0, 0);
            }
        }
    }

    // epilogue: C row = g*4 + reg, col = l15
    float li[4];
    #pragma unroll
    for (int r = 0; r < 4; ++r)
        li[r] = linv[(size_t)(b * NN + i0 + wv * 16 + g * 4 + r) * HEADS + h];
    #pragma unroll
    for (int n = 0; n < 4; ++n) {
        #pragma unroll
        for (int r = 0; r < 4; ++r) {
            const int io = i0 + wv * 16 + g * 4 + r;
            out[(size_t)(b * NN + io) * NH + h * 64 + n * 16 + l15] = acc[n][r] * li[r];
        }
    }
}

// ---------------------------------------------------------------------------
extern "C" void kernel_launch(void* const* d_in, const int* in_sizes, int n_in,
                              void* d_out, int out_size, void* d_ws, size_t ws_size,
                              hipStream_t stream) {
    const float* h   = (const float*)d_in[0];
    const int*   adj = (const int*)  d_in[1];
    const float* W   = (const float*)d_in[2];
    const float* a   = (const float*)d_in[3];
    float* out = (float*)d_out;

    float* ws   = (float*)d_ws;
    float* Wh   = ws;                                  // 8192*512 f32
    float* esrc = Wh   + (size_t)BS * NN * NH;         // 8192*8
    float* edst = esrc + (size_t)BS * NN * HEADS;
    float* mrow = edst + (size_t)BS * NN * HEADS;
    float* lin  = mrow + (size_t)BS * NN * HEADS;
    unsigned* bits = (unsigned*)(lin + (size_t)BS * NN * HEADS);  // 8192*32 u32

    gemm_wh      <<<dim3(NH / 64, (BS * NN) / 64), 256, 0, stream>>>(h, W, Wh);
    calc_e       <<<BS * NN, 512, 0, stream>>>(Wh, a, esrc, edst);
    pack_adj     <<<(BS * NN * NN) / 256, 256, 0, stream>>>(adj, bits);
    softmax_stats<<<(BS * NN) / 4, 256, 0, stream>>>(bits, esrc, edst, mrow, lin);
    attn_pv_mfma <<<dim3(16, HEADS, BS), 256, 0, stream>>>(bits, Wh, esrc, edst, mrow, lin, out);
}

// Round 3
// 72.268 us; speedup vs baseline: 5.0276x; 2.3293x over previous
//
#include <hip/hip_runtime.h>
#include <hip/hip_bf16.h>
#include <math.h>

#define BS 8
#define NN 1024
#define FIN 256
#define HEADS 8
#define FO 64
#define NH (HEADS*FO)   /* 512 */
static constexpr float ALPHA = 0.2f;
static constexpr float LOG2E = 1.4426950408889634f;

typedef short bf16x8 __attribute__((ext_vector_type(8)));
typedef float f32x4  __attribute__((ext_vector_type(4)));
typedef unsigned short u16;
typedef u16 u16x8 __attribute__((ext_vector_type(8)));
typedef u16 u16x4 __attribute__((ext_vector_type(4)));

__device__ __forceinline__ u16 f2b(float x) {
    __hip_bfloat16 b = __float2bfloat16(x);
    return *reinterpret_cast<u16*>(&b);
}

// async global->LDS, 16B per lane: LDS dest = uniform base + lane*16 (linear),
// global src is PER-LANE (pre-swizzled by caller).
__device__ __forceinline__ void gload_lds16(const u16* g, u16* l) {
    __builtin_amdgcn_global_load_lds(
        (const __attribute__((address_space(1))) unsigned int*)g,
        (__attribute__((address_space(3))) unsigned int*)l,
        16, 0, 0);
}

// ---------------------------------------------------------------------------
// cvt_h: h f32 -> bf16, 8 elems/thread
// ---------------------------------------------------------------------------
__global__ __launch_bounds__(256) void cvt_h(const float* __restrict__ h,
                                             u16* __restrict__ hb) {
    const int i = (blockIdx.x * 256 + threadIdx.x) * 8;
    const float4 v0 = *reinterpret_cast<const float4*>(h + i);
    const float4 v1 = *reinterpret_cast<const float4*>(h + i + 4);
    u16x8 o;
    o[0]=f2b(v0.x); o[1]=f2b(v0.y); o[2]=f2b(v0.z); o[3]=f2b(v0.w);
    o[4]=f2b(v1.x); o[5]=f2b(v1.y); o[6]=f2b(v1.z); o[7]=f2b(v1.w);
    *reinterpret_cast<u16x8*>(hb + i) = o;
}

// ---------------------------------------------------------------------------
// cvt_wT: W[256][512] f32 -> WbT[512][256] bf16 (LDS transpose)
// ---------------------------------------------------------------------------
__global__ __launch_bounds__(256) void cvt_wT(const float* __restrict__ W,
                                              u16* __restrict__ WbT) {
    __shared__ float T[64][65];
    const int n0 = blockIdx.x * 64, k0 = blockIdx.y * 64;
    const int t = threadIdx.x;
    const int r4 = t >> 6, c = t & 63;
    #pragma unroll
    for (int p = 0; p < 16; ++p) {
        const int r = p * 4 + r4;
        T[r][c] = W[(size_t)(k0 + r) * NH + n0 + c];
    }
    __syncthreads();
    #pragma unroll
    for (int p = 0; p < 16; ++p) {
        const int r = p * 4 + r4;
        WbT[(size_t)(n0 + r) * FIN + k0 + c] = f2b(T[c][r]);
    }
}

// ---------------------------------------------------------------------------
// pack_adj: adjacency -> bitmask (32 MB -> 1 MB)
// ---------------------------------------------------------------------------
__global__ __launch_bounds__(256) void pack_adj(const int* __restrict__ adj,
                                                unsigned* __restrict__ bits) {
    const size_t gid = (size_t)blockIdx.x * 256 + threadIdx.x;
    const int av = adj[gid];
    const unsigned long long mask = __ballot(av != 0);
    const int lane = threadIdx.x & 63;
    if ((lane & 31) == 0)
        bits[gid >> 5] = (unsigned)(lane ? (mask >> 32) : mask);
}

// ---------------------------------------------------------------------------
// gemm_whT: Wh = h @ W via bf16 MFMA. Block = (m-tile 128, head), 4 waves.
// Outputs: WhT[bh][f][i] bf16 (transposed), esrc2/edst2 = e*log2e (f32,
// from f32 accumulators, pre-bf16-rounding).
// ---------------------------------------------------------------------------
__global__ __launch_bounds__(256) void gemm_whT(const u16* __restrict__ hb,
                                                const u16* __restrict__ WbT,
                                                const float* __restrict__ avec,
                                                u16* __restrict__ WhT,
                                                float* __restrict__ esrc2,
                                                float* __restrict__ edst2) {
    __shared__ u16 Al[2][128 * 64];   // [m][k-chunk swizzled]
    __shared__ u16 Bl[2][64 * 64];    // [n][k-chunk swizzled]
    const int t = threadIdx.x, wv = t >> 6, lane = t & 63;
    const int g = lane >> 4, l15 = lane & 15;
    const int m0 = blockIdx.x * 128;
    const int h  = blockIdx.y;
    const int lr = lane >> 3;                 // row-sub 0..7 within 8-row group
    const int sch = (lane & 7) ^ lr;          // swizzled source chunk

    f32x4 acc[2][4] = {};

    auto stageA = [&](int buf, int k0) {
        #pragma unroll
        for (int c = 0; c < 4; ++c) {
            const int rowb = wv * 32 + c * 8;
            gload_lds16(hb + (size_t)(m0 + rowb + lr) * FIN + k0 + sch * 8,
                        &Al[buf][rowb * 64]);
        }
    };
    auto stageB = [&](int buf, int k0) {
        #pragma unroll
        for (int c = 0; c < 2; ++c) {
            const int rowb = wv * 16 + c * 8;
            gload_lds16(WbT + (size_t)(h * 64 + rowb + lr) * FIN + k0 + sch * 8,
                        &Bl[buf][rowb * 64]);
        }
    };

    stageA(0, 0); stageB(0, 0);
    __syncthreads();
    for (int kt = 0; kt < 4; ++kt) {          // K = 4 x 64
        const int buf = kt & 1;
        if (kt < 3) { stageA(buf ^ 1, (kt + 1) * 64); stageB(buf ^ 1, (kt + 1) * 64); }
        #pragma unroll
        for (int ks = 0; ks < 2; ++ks) {
            const int ch = (ks * 4 + g) ^ (l15 & 7);
            bf16x8 afr[2];
            #pragma unroll
            for (int mf = 0; mf < 2; ++mf)
                afr[mf] = *reinterpret_cast<const bf16x8*>(
                    &Al[buf][(wv * 32 + mf * 16 + l15) * 64 + ch * 8]);
            #pragma unroll
            for (int n = 0; n < 4; ++n) {
                const bf16x8 bfr = *reinterpret_cast<const bf16x8*>(
                    &Bl[buf][(n * 16 + l15) * 64 + ch * 8]);
                acc[0][n] = __builtin_amdgcn_mfma_f32_16x16x32_bf16(afr[0], bfr, acc[0][n], 0, 0, 0);
                acc[1][n] = __builtin_amdgcn_mfma_f32_16x16x32_bf16(afr[1], bfr, acc[1][n], 0, 0, 0);
            }
        }
        __syncthreads();
    }

    // a vectors for this head
    float as[4], ad[4];
    #pragma unroll
    for (int n = 0; n < 4; ++n) {
        as[n] = avec[h * 128 + n * 16 + l15];
        ad[n] = avec[h * 128 + 64 + n * 16 + l15];
    }
    const int bh = (m0 >> 10) * HEADS + h;    // m-tile never crosses batch
    // e epilogue from f32 acc: reduce over 16 l15 lanes
    #pragma unroll
    for (int mf = 0; mf < 2; ++mf) {
        #pragma unroll
        for (int r = 0; r < 4; ++r) {
            float es = 0.f, ed = 0.f;
            #pragma unroll
            for (int n = 0; n < 4; ++n) {
                es += acc[mf][n][r] * as[n];
                ed += acc[mf][n][r] * ad[n];
            }
            #pragma unroll
            for (int off = 1; off < 16; off <<= 1) {
                es += __shfl_xor(es, off);
                ed += __shfl_xor(ed, off);
            }
            if (l15 == 0) {
                const int gm = m0 + wv * 32 + mf * 16 + g * 4 + r;
                const int ii = gm & (NN - 1);
                esrc2[(size_t)bh * NN + ii] = es * LOG2E;
                edst2[(size_t)bh * NN + ii] = ed * LOG2E;
            }
        }
    }
    // transposed bf16 store: WhT[bh][f][i], 4 consecutive i per lane (8B)
    #pragma unroll
    for (int mf = 0; mf < 2; ++mf) {
        const int gm0 = m0 + wv * 32 + mf * 16 + g * 4;
        const int ii0 = gm0 & (NN - 1);
        #pragma unroll
        for (int n = 0; n < 4; ++n) {
            u16x4 pk;
            #pragma unroll
            for (int r = 0; r < 4; ++r) pk[r] = f2b(acc[mf][n][r]);
            *reinterpret_cast<u16x4*>(
                &WhT[((size_t)bh * 64 + n * 16 + l15) * NN + ii0]) = pk;
        }
    }
}

// ---------------------------------------------------------------------------
// attn_pv: out = softmax(masked lrelu(e)) @ Wh, fused denominator (m=0).
// Block = (64-row i-tile, h, b), 4 waves; wave owns 16 rows x 64 f.
// WhT tile staged via global_load_lds + XOR chunk swizzle.
// ---------------------------------------------------------------------------
__global__ __launch_bounds__(256) void attn_pv(const unsigned* __restrict__ bits,
                                               const u16* __restrict__ WhT,
                                               const float* __restrict__ esrc2,
                                               const float* __restrict__ edst2,
                                               float* __restrict__ out) {
    __shared__ u16 Bs[2][64 * 64];            // [f][j-chunk swizzled]
    const int t = threadIdx.x, wv = t >> 6, lane = t & 63;
    const int g = lane >> 4, l15 = lane & 15;
    const int i0 = blockIdx.x * 64;
    const int h  = blockIdx.y, b = blockIdx.z;
    const int bh = b * HEADS + h;
    const int lr = lane >> 3;
    const int sch = (lane & 7) ^ lr;

    const int rowi = i0 + wv * 16 + l15;
    const float es2 = esrc2[(size_t)bh * NN + rowi];
    const unsigned* bitrow = bits + (size_t)(b * NN + rowi) * 32;
    const float* ed2 = edst2 + (size_t)bh * NN;
    const u16* whb = WhT + (size_t)bh * 64 * NN;

    auto stage = [&](int buf, int j0) {
        #pragma unroll
        for (int c = 0; c < 2; ++c) {
            const int fb = wv * 16 + c * 8;
            gload_lds16(whb + (size_t)(fb + lr) * NN + j0 + sch * 8,
                        &Bs[buf][fb * 64]);
        }
    };

    f32x4 acc[4] = {};
    float lrun = 0.f;
    stage(0, 0);
    __syncthreads();
    for (int tt = 0; tt < 16; ++tt) {
        const int buf = tt & 1;
        if (tt < 15) stage(buf ^ 1, (tt + 1) * 64);
        const int j0 = tt * 64;
        #pragma unroll
        for (int ks = 0; ks < 2; ++ks) {
            const int jb = j0 + ks * 32;
            const unsigned word = bitrow[jb >> 5];
            const unsigned byte = (word >> (8 * g)) & 0xffu;
            const float4 d0 = *reinterpret_cast<const float4*>(ed2 + jb + 8 * g);
            const float4 d1 = *reinterpret_cast<const float4*>(ed2 + jb + 8 * g + 4);
            bf16x8 af;
            #pragma unroll
            for (int q = 0; q < 8; ++q) {
                float s = es2 + ((q < 4) ? (&d0.x)[q] : (&d1.x)[q - 4]);
                s = fmaxf(s, ALPHA * s);                  // lrelu (scaled domain)
                s = ((byte >> q) & 1u) ? s : -1e30f;      // mask -> exp2 = 0
                const float p = exp2f(s);
                lrun += p;
                af[q] = (short)f2b(p);
            }
            const int ch = (ks * 4 + g) ^ (l15 & 7);
            #pragma unroll
            for (int n = 0; n < 4; ++n) {
                const bf16x8 bfr = *reinterpret_cast<const bf16x8*>(
                    &Bs[buf][(n * 16 + l15) * 64 + ch * 8]);
                acc[n] = __builtin_amdgcn_mfma_f32_16x16x32_bf16(af, bfr, acc[n], 0, 0, 0);
            }
        }
        __syncthreads();
    }
    // full row-denominator: combine the 4 g-lanes of each row
    lrun += __shfl_xor(lrun, 16);
    lrun += __shfl_xor(lrun, 32);
    float inv[4];
    #pragma unroll
    for (int r = 0; r < 4; ++r) inv[r] = 1.0f / __shfl(lrun, g * 4 + r);
    #pragma unroll
    for (int n = 0; n < 4; ++n) {
        #pragma unroll
        for (int r = 0; r < 4; ++r) {
            const int io = i0 + wv * 16 + g * 4 + r;
            out[(size_t)(b * NN + io) * NH + h * 64 + n * 16 + l15] = acc[n][r] * inv[r];
        }
    }
}

// ---------------------------------------------------------------------------
extern "C" void kernel_launch(void* const* d_in, const int* in_sizes, int n_in,
                              void* d_out, int out_size, void* d_ws, size_t ws_size,
                              hipStream_t stream) {
    const float* h   = (const float*)d_in[0];
    const int*   adj = (const int*)  d_in[1];
    const float* W   = (const float*)d_in[2];
    const float* a   = (const float*)d_in[3];
    float* out = (float*)d_out;

    char* ws = (char*)d_ws;
    u16*   hb    = (u16*)ws;                                   ws += (size_t)BS*NN*FIN*2;
    u16*   WbT   = (u16*)ws;                                   ws += (size_t)NH*FIN*2;
    u16*   WhT   = (u16*)ws;                                   ws += (size_t)BS*HEADS*64*NN*2;
    float* esrc2 = (float*)ws;                                 ws += (size_t)BS*HEADS*NN*4;
    float* edst2 = (float*)ws;                                 ws += (size_t)BS*HEADS*NN*4;
    unsigned* bits = (unsigned*)ws;

    cvt_h   <<<(BS*NN*FIN)/(256*8), 256, 0, stream>>>(h, hb);
    cvt_wT  <<<dim3(NH/64, FIN/64), 256, 0, stream>>>(W, WbT);
    pack_adj<<<(BS*NN*NN)/256, 256, 0, stream>>>(adj, bits);
    gemm_whT<<<dim3((BS*NN)/128, HEADS), 256, 0, stream>>>(hb, WbT, a, WhT, esrc2, edst2);
    attn_pv <<<dim3(NN/64, HEADS, BS), 256, 0, stream>>>(bits, WhT, esrc2, edst2, out);
}